// Round 9
// baseline (149.297 us; speedup 1.0000x reference)
//
#include <hip/hip_runtime.h>
#include <math.h>

#define BB 16
#define PP 16384
#define TT 64
#define CC 85
#define PRED_PER_BLK 512
#define CHUNKS (PP / PRED_PER_BLK)   // 32
#define NBLK (BB * CHUNKS)           // 512

typedef float float4u __attribute__((ext_vector_type(4), aligned(4)));

// ws layout (floats):
// [0 .. 65535]     cand float2[b][chunk][t]  (16*32*64 float2 = 256 KB)
// [65536 .. 66047] conf_part[512]
// [66048 .. 67071] loss_bt[1024]
// [67072 .. 68095] matched[1024] (int)
// [68096 .. 68097] barrier counters c0,c1 (zeroed via hipMemsetAsync each call)

__device__ __forceinline__ void gridbar(unsigned int* cnt) {
    __syncthreads();
    if (threadIdx.x == 0) {
        __threadfence();   // release: make our ws stores visible device-wide
        __hip_atomic_fetch_add(cnt, 1u, __ATOMIC_ACQ_REL, __HIP_MEMORY_SCOPE_AGENT);
        unsigned int spins = 0;
        while (__hip_atomic_load(cnt, __ATOMIC_ACQUIRE, __HIP_MEMORY_SCOPE_AGENT) < (unsigned)NBLK) {
            __builtin_amdgcn_s_sleep(2);
            if (++spins > 100000000u) break;   // graceful anti-hang bound
        }
        __threadfence();   // acquire
    }
    __syncthreads();
}

__global__ __launch_bounds__(256, 2) void fused_kernel(const float* __restrict__ raw,
                                                       const float* __restrict__ tgt,
                                                       float* __restrict__ wsf,
                                                       float* __restrict__ out) {
    float2* cand    = (float2*)wsf;
    float*  conf_p  = wsf + 65536;
    float*  loss_bt = wsf + 66048;
    int*    matched = (int*)(wsf + 67072);
    unsigned int* bar = (unsigned int*)(wsf + 68096);

    int tid  = threadIdx.x;
    int wave = tid >> 6, lane = tid & 63;
    int b     = blockIdx.x / CHUNKS;
    int chunk = blockIdx.x % CHUNKS;
    int p0    = chunk * PRED_PER_BLK;

    __shared__ float4 sbox[PRED_PER_BLK];      // 8 KB
    __shared__ float  sbi[4][64], sbu[4][64];  // candidate (inter, union) pairs
    __shared__ int    sbidx[4][64];
    __shared__ float  sconf[4];
    __shared__ int    sm[BB * TT];             // phase C
    __shared__ float  wsum[4];

    // ---------------- Phase A: IoU scan + conf softplus ----------------
    const float* base = raw + (size_t)b * PP * CC;
    float ca = 0.0f;
    for (int r = tid; r < PRED_PER_BLK; r += 256) {
        const float* pr = base + (size_t)(p0 + r) * CC;
        float4u bx = *(const float4u*)pr;
        float c = pr[4];
        sbox[r] = make_float4(bx.x, bx.y, bx.z, bx.w);
        ca += fmaxf(c, 0.0f) + log1pf(expf(-fabsf(c)));
    }
    for (int m = 32; m > 0; m >>= 1) ca += __shfl_xor(ca, m);
    if (lane == 0) sconf[wave] = ca;
    __syncthreads();

    const float* trow = tgt + (size_t)(b * TT + lane) * 5;
    float tx1 = trow[0], ty1 = trow[1], tx2 = trow[2], ty2 = trow[3];
    float area_t = (tx2 - tx1) * (ty2 - ty1);

    // Best tracked as (inter, union) pair; compare a/b > c/d via ad > cb (b,d > 0).
    float bi = -1.0f, bu = 1.0f;
    int bidx = p0;
    int j0 = wave * (PRED_PER_BLK / 4);
#pragma unroll 4
    for (int j = 0; j < PRED_PER_BLK / 4; ++j) {
        float4 pb = sbox[j0 + j];                       // uniform -> LDS broadcast
        float ap = (pb.z - pb.x) * (pb.w - pb.y);       // recompute: VALU cheaper than 2nd ds_read
        float x1 = fmaxf(pb.x, tx1), y1 = fmaxf(pb.y, ty1);
        float x2 = fminf(pb.z, tx2), y2 = fminf(pb.w, ty2);
        float w = x2 - x1, h = y2 - y1;
        float inter = w * h;
        float uni = (ap + area_t) - inter;
        bool ok = (w > 0.0f) && (h > 0.0f) && (uni > 0.0f);
        float ie = ok ? inter : 0.0f;
        float ue = ok ? uni : 1.0f;
        if (ie * bu > bi * ue) { bi = ie; bu = ue; bidx = p0 + j0 + j; }  // ascending -> first max
    }
    sbi[wave][lane] = bi; sbu[wave][lane] = bu; sbidx[wave][lane] = bidx;
    __syncthreads();

    if (tid == 0) conf_p[blockIdx.x] = (sconf[0] + sconf[1]) + (sconf[2] + sconf[3]);

    if (wave == 0) {
        float i1 = sbi[0][lane], u1 = sbu[0][lane];
        int ix = sbidx[0][lane];
        for (int w2 = 1; w2 < 4; ++w2) {                 // ascending ranges: strict > keeps first
            float i2 = sbi[w2][lane], u2 = sbu[w2][lane];
            if (i2 * u1 > i1 * u2) { i1 = i2; u1 = u2; ix = sbidx[w2][lane]; }
        }
        float iou = fmaxf(i1, 0.0f) / u1;                // one division per candidate
        cand[((size_t)b * CHUNKS + chunk) * TT + lane] = make_float2(iou, __int_as_float(ix));
    }

    gridbar(&bar[0]);

    // ---------------- Phase B: per-target finalize (1024 wave-units) ----------------
    if (wave < 2) {
        int bt = blockIdx.x * 2 + wave;
        int b2 = bt >> 6, t2 = bt & 63;
        float v = -2.0f; int idx = 0x7fffffff;
        if (lane < CHUNKS) {
            float2 c2 = cand[((size_t)b2 * CHUNKS + lane) * TT + t2];
            v = c2.x; idx = __float_as_int(c2.y);
        }
        for (int m = 1; m < 64; m <<= 1) {
            float ov = __shfl_xor(v, m); int oi = __shfl_xor(idx, m);
            if (ov > v || (ov == v && oi < idx)) { v = ov; idx = oi; }
        }
        const float* prow = raw + ((size_t)b2 * PP + idx) * CC;
        float l0 = prow[5 + lane];
        float l1 = (lane < 16) ? prow[69 + lane] : -INFINITY;
        float mx = fmaxf(l0, l1);
        for (int m = 1; m < 64; m <<= 1) mx = fmaxf(mx, __shfl_xor(mx, m));
        float e = expf(l0 - mx) + ((lane < 16) ? expf(l1 - mx) : 0.0f);
        for (int m = 1; m < 64; m <<= 1) e += __shfl_xor(e, m);
        if (lane == 0) {
            const float* tr2 = tgt + (size_t)bt * 5;
            int tcls = (int)tr2[4];
            float cls = (mx + logf(e)) - prow[5 + tcls];
            float bxl = 0.0f;
            for (int k = 0; k < 4; ++k) {
                float d = fabsf(prow[k] - tr2[k]);
                bxl += (d < 1.0f) ? 0.5f * d * d : (d - 0.5f);
            }
            loss_bt[bt] = 5.0f * bxl + cls;
            matched[bt] = idx;
        }
    }

    gridbar(&bar[1]);

    // ---------------- Phase C: dedupe + final sum (one block) ----------------
    if (blockIdx.x != NBLK - 1) return;

    for (int i = tid; i < BB * TT; i += 256) sm[i] = matched[i];
    __syncthreads();

    float acc = 0.0f;
    for (int i = tid; i < BB * TT; i += 256) {
        int m = sm[i];
        bool first = true;
        for (int t3 = i & ~63; t3 < i; ++t3)
            if (sm[t3] == m) { first = false; break; }
        float sub = first ? raw[((size_t)(i >> 6) * PP + m) * CC + 4] : 0.0f;
        acc += loss_bt[i] - sub;
    }
    for (int i = tid; i < NBLK; i += 256) acc += conf_p[i];

    for (int m = 32; m > 0; m >>= 1) acc += __shfl_xor(acc, m);
    if (lane == 0) wsum[wave] = acc;
    __syncthreads();
    if (tid == 0) out[0] = ((wsum[0] + wsum[1]) + (wsum[2] + wsum[3])) / (float)BB;
}

extern "C" void kernel_launch(void* const* d_in, const int* in_sizes, int n_in,
                              void* d_out, int out_size, void* d_ws, size_t ws_size,
                              hipStream_t stream) {
    const float* raw = (const float*)d_in[0];
    const float* tgt = (const float*)d_in[1];
    float* out = (float*)d_out;
    float* wsf = (float*)d_ws;

    // zero the two barrier counters each call (graph-capture-safe)
    hipMemsetAsync(wsf + 68096, 0, 8, stream);
    fused_kernel<<<NBLK, 256, 0, stream>>>(raw, tgt, wsf, out);
}

// Round 10
// 57.791 us; speedup vs baseline: 2.5834x; 2.5834x over previous
//
#include <hip/hip_runtime.h>
#include <math.h>

#define BB 16
#define PP 16384
#define TT 64
#define CC 85
#define PRED_PER_BLK 512
#define CHUNKS (PP / PRED_PER_BLK)   // 32
#define NBLK (BB * CHUNKS)           // 512

typedef float float4u __attribute__((ext_vector_type(4), aligned(4)));

// ws layout (floats):
// [0..2047]      keys u64[1024]   -- zeroed each call by hipMemsetAsync (poison-safe)
// [2048..2064]   tick u32[17]     -- zeroed each call (same memset: 8260 B total)
// [2080..2591]   conf_part[512]   -- relaxed-atomic stores, written before read
// [2592..2607]   batch_part[16]   -- relaxed-atomic stores, written before read
//
// All cross-block data flows through atomic ops (coherence point), ordered by
// wave-local s_waitcnt vmcnt(0) + ACQ_REL ticket RMWs. No spins, no barriers.

__global__ __launch_bounds__(256, 2) void fused_kernel(const float* __restrict__ raw,
                                                       const float* __restrict__ tgt,
                                                       float* __restrict__ wsf,
                                                       float* __restrict__ out) {
#pragma clang fp contract(off)
    unsigned long long* keys = (unsigned long long*)wsf;
    unsigned int* tick  = (unsigned int*)(wsf + 2048);
    float* conf_part    = wsf + 2080;
    float* batch_part   = wsf + 2592;

    int tid = threadIdx.x, wave = tid >> 6, lane = tid & 63;
    int b = blockIdx.x / CHUNKS, chunk = blockIdx.x % CHUNKS;
    int p0 = chunk * PRED_PER_BLK;

    __shared__ float4 sbox[PRED_PER_BLK];      // 8 KB
    __shared__ float  sbi[4][64], sbu[4][64];
    __shared__ int    sbidx[4][64];
    __shared__ float  sconf[4];
    __shared__ int    swin;
    __shared__ int    smatch[TT];
    __shared__ float  sloss[TT];

    // ---------------- Phase A: stage + IoU scan + conf softplus ----------------
    const float* base = raw + (size_t)b * PP * CC;
    float ca = 0.0f;
    for (int r = tid; r < PRED_PER_BLK; r += 256) {
        const float* pr = base + (size_t)(p0 + r) * CC;
        float4u bx = *(const float4u*)pr;
        float c = pr[4];
        sbox[r] = make_float4(bx.x, bx.y, bx.z, bx.w);
        ca += fmaxf(c, 0.0f) + log1pf(expf(-fabsf(c)));
    }
    for (int m = 32; m > 0; m >>= 1) ca += __shfl_xor(ca, m);
    if (lane == 0) sconf[wave] = ca;
    __syncthreads();

    const float* trow = tgt + (size_t)(b * TT + lane) * 5;
    float tx1 = trow[0], ty1 = trow[1], tx2 = trow[2], ty2 = trow[3];
    float area_t = (tx2 - tx1) * (ty2 - ty1);

    // Best as (inter, union): a/b > c/d  <=>  a*d > c*b  (b,d > 0). Bit-exact
    // argmax semantics field-proven in R9 (absmax 0.0).
    float bi = -1.0f, bu = 1.0f;
    int bidx = p0;
    int j0 = wave * (PRED_PER_BLK / 4);
#pragma unroll 4
    for (int j = 0; j < PRED_PER_BLK / 4; ++j) {
        float4 pb = sbox[j0 + j];                    // uniform -> LDS broadcast
        float ap = (pb.z - pb.x) * (pb.w - pb.y);
        float x1 = fmaxf(pb.x, tx1), y1 = fmaxf(pb.y, ty1);
        float x2 = fminf(pb.z, tx2), y2 = fminf(pb.w, ty2);
        float w = x2 - x1, h = y2 - y1;
        float inter = w * h;
        float uni = (ap + area_t) - inter;
        bool ok = (w > 0.0f) && (h > 0.0f) && (uni > 0.0f);
        float ie = ok ? inter : 0.0f;
        float ue = ok ? uni : 1.0f;
        if (ie * bu > bi * ue) { bi = ie; bu = ue; bidx = p0 + j0 + j; }
    }
    sbi[wave][lane] = bi; sbu[wave][lane] = bu; sbidx[wave][lane] = bidx;
    __syncthreads();

    if (wave == 0) {
        float i1 = sbi[0][lane], u1 = sbu[0][lane];
        int ix = sbidx[0][lane];
        for (int w2 = 1; w2 < 4; ++w2) {             // ascending ranges: strict > keeps first
            float i2 = sbi[w2][lane], u2 = sbu[w2][lane];
            if (i2 * u1 > i1 * u2) { i1 = i2; u1 = u2; ix = sbidx[w2][lane]; }
        }
        float iou = fmaxf(i1, 0.0f) / u1;
        // (max iou, min idx) lexicographic; iou>=0 so sign bit is 0.
        unsigned long long key =
            ((unsigned long long)__float_as_uint(iou) << 32) | (unsigned)(~ix);
        atomicMax(&keys[b * TT + lane], key);        // RMW at coherence point

        if (lane == 0) {
            float cs = (sconf[0] + sconf[1]) + (sconf[2] + sconf[3]);
            __hip_atomic_store(&conf_part[blockIdx.x], cs,
                               __ATOMIC_RELAXED, __HIP_MEMORY_SCOPE_AGENT);
        }
        asm volatile("s_waitcnt vmcnt(0)" ::: "memory");   // all wave0 atomics done
        if (lane == 0) {
            unsigned old = __hip_atomic_fetch_add(&tick[b], 1u,
                               __ATOMIC_ACQ_REL, __HIP_MEMORY_SCOPE_AGENT);
            swin = (old == CHUNKS - 1);              // last arriver owns batch tail
        }
    }
    __syncthreads();
    if (!swin) return;

    // ---------------- Phase B: batch tail (winner block, all 4 waves) ----------------
    if (tid < TT) {
        unsigned long long k = __hip_atomic_load(&keys[b * TT + tid],
                                  __ATOMIC_RELAXED, __HIP_MEMORY_SCOPE_AGENT);
        smatch[tid] = (int)(~(unsigned)(k & 0xFFFFFFFFull));
    }
    __syncthreads();

    for (int it = 0; it < 16; ++it) {
        int t = wave * 16 + it;
        int idx = smatch[t];
        const float* prow = raw + ((size_t)b * PP + idx) * CC;
        float l0 = prow[5 + lane];
        float l1 = (lane < 16) ? prow[69 + lane] : -INFINITY;
        float mx = fmaxf(l0, l1);
        for (int m = 1; m < 64; m <<= 1) mx = fmaxf(mx, __shfl_xor(mx, m));
        float e = expf(l0 - mx) + ((lane < 16) ? expf(l1 - mx) : 0.0f);
        for (int m = 1; m < 64; m <<= 1) e += __shfl_xor(e, m);
        if (lane == 0) {
            const float* tr2 = tgt + (size_t)(b * TT + t) * 5;
            int tcls = (int)tr2[4];
            float cls = (mx + logf(e)) - prow[5 + tcls];
            float bxl = 0.0f;
            for (int k2 = 0; k2 < 4; ++k2) {
                float d = fabsf(prow[k2] - tr2[k2]);
                bxl += (d < 1.0f) ? 0.5f * d * d : (d - 0.5f);
            }
            sloss[t] = 5.0f * bxl + cls;
        }
    }
    __syncthreads();
    if (wave != 0) return;

    // Dedupe + conf slice + batch sum (wave0 only; fixed order => deterministic).
    int mIdx = smatch[lane];
    bool first = true;
    for (int t2 = 0; t2 < lane; ++t2)
        if (smatch[t2] == mIdx) { first = false; break; }
    float sub = first ? raw[((size_t)b * PP + mIdx) * CC + 4] : 0.0f;
    float a = sloss[lane] - sub;
    if (lane < CHUNKS)
        a += __hip_atomic_load(&conf_part[b * CHUNKS + lane],
                               __ATOMIC_RELAXED, __HIP_MEMORY_SCOPE_AGENT);
    for (int mm = 1; mm < 64; mm <<= 1) a += __shfl_xor(a, mm);

    if (lane == 0)
        __hip_atomic_store(&batch_part[b], a,
                           __ATOMIC_RELAXED, __HIP_MEMORY_SCOPE_AGENT);
    asm volatile("s_waitcnt vmcnt(0)" ::: "memory");
    unsigned o2 = 0;
    if (lane == 0)
        o2 = __hip_atomic_fetch_add(&tick[BB], 1u,
                 __ATOMIC_ACQ_REL, __HIP_MEMORY_SCOPE_AGENT);
    int lastf = (lane == 0 && o2 == BB - 1) ? 1 : 0;
    lastf = __shfl(lastf, 0);
    if (!lastf) return;

    // ---------------- Phase C: final 16-way sum (one wave, once) ----------------
    float v = (lane < BB) ? __hip_atomic_load(&batch_part[lane],
                                __ATOMIC_RELAXED, __HIP_MEMORY_SCOPE_AGENT)
                          : 0.0f;
    for (int mm = 1; mm < 64; mm <<= 1) v += __shfl_xor(v, mm);
    if (lane == 0) out[0] = v / (float)BB;
}

extern "C" void kernel_launch(void* const* d_in, const int* in_sizes, int n_in,
                              void* d_out, int out_size, void* d_ws, size_t ws_size,
                              hipStream_t stream) {
    const float* raw = (const float*)d_in[0];
    const float* tgt = (const float*)d_in[1];
    float* out = (float*)d_out;
    float* wsf = (float*)d_ws;

    // zero keys (8192 B) + tickets (68 B) each call; graph-capture-safe
    hipMemsetAsync(wsf, 0, 8260, stream);
    fused_kernel<<<NBLK, 256, 0, stream>>>(raw, tgt, wsf, out);
}